// Round 1
// baseline (253.515 us; speedup 1.0000x reference)
//
#include <hip/hip_runtime.h>
#include <hip/hip_bf16.h>

#define BS   128
#define HDIM 512
#define NNODE 1024
#define BN   64
#define NT   (NNODE/BN)    // 16 tiles per batch
#define NBLK (BS*NT)       // 2048 blocks

typedef __bf16 bf16x8 __attribute__((ext_vector_type(8)));
typedef float  f32x4  __attribute__((ext_vector_type(4)));

__device__ __forceinline__ unsigned short f2bf(float x) {
    unsigned int u = __builtin_bit_cast(unsigned int, x);
    unsigned int r = (u + 0x7FFFu + ((u >> 16) & 1u)) >> 16;
    return (unsigned short)r;
}

__device__ __forceinline__ float tanh_fast(float x) {
    float e = __expf(2.0f * x);
    return 1.0f - 2.0f / (e + 1.0f);
}

// ---- kernel 1: cast W_ref (f32 [512][512]) -> bf16 ----
__global__ void k_cast_w(const float* __restrict__ W, unsigned short* __restrict__ Wb) {
    int i = (blockIdx.x * 256 + threadIdx.x) * 4;
    float4 v = *(const float4*)(W + i);
    ushort4 o;
    o.x = f2bf(v.x); o.y = f2bf(v.y); o.z = f2bf(v.z); o.w = f2bf(v.w);
    *(ushort4*)(Wb + i) = o;
}

// ---- kernel 2: u1b[b][o] = (q @ W_q^T + b_q)[b][o] + b_ref[o]  (fp32 exact) ----
__global__ void k_u1(const float* __restrict__ q, const float* __restrict__ Wq,
                     const float* __restrict__ bq, const float* __restrict__ bref,
                     float* __restrict__ u1b) {
    __shared__ float ql[HDIM];
    int b = blockIdx.x, o = threadIdx.x;
    ql[o] = q[b * HDIM + o];
    __syncthreads();
    float acc = bq[o] + bref[o];
    const float* wr = Wq + (size_t)o * HDIM;
    #pragma unroll 4
    for (int h = 0; h < HDIM; h += 4) {
        float4 w = *(const float4*)(wr + h);
        acc += w.x * ql[h] + w.y * ql[h + 1] + w.z * ql[h + 2] + w.w * ql[h + 3];
    }
    u1b[b * HDIM + o] = acc;
}

// ---- kernel 3: main fused tile kernel ----
// block = (batch b, node-tile t of 64). 8 waves; wave w owns output rows [w*64, w*64+64).
// u2_tile = W_ref(bf16) @ ref_tile(bf16) via MFMA (f32 acc); scores from acc regs;
// local softmax (m_t, l_t); d_t = sum_n w_n * acc[:,n]; write (m_t,l_t,d_t) to ws.
__launch_bounds__(512, 2)
__global__ void k_main(const float* __restrict__ ref, const int* __restrict__ mask,
                       const float* __restrict__ v, const unsigned short* __restrict__ Wb,
                       const float* __restrict__ u1b,
                       float* __restrict__ stats, float* __restrict__ dts)
{
    __shared__ unsigned short Bs[64 * 512];   // [n][k] bf16, slot-swizzled, 64 KB
    __shared__ float u1l[HDIM];
    __shared__ float vl[HDIM];
    __shared__ float sred[8][BN];
    __shared__ float wts[BN];

    const int bid = blockIdx.x;
    const int b = bid >> 4;
    const int t = bid & 15;
    const int n0 = t * BN;
    const int tid = threadIdx.x;
    const int wave = tid >> 6;
    const int lane = tid & 63;
    const int cl = lane & 15;     // col-in-fragment
    const int gr = lane >> 4;     // k-group / row-group

    u1l[tid] = u1b[b * HDIM + tid];
    vl[tid]  = v[tid];

    // ---- stage ref tile [512 h][64 n] f32 -> LDS [n][k=h] bf16 with swizzle ----
    const float* refb = ref + (size_t)b * HDIM * NNODE + n0;
    #pragma unroll
    for (int i = 0; i < 4; i++) {
        int mt = tid + 512 * i;        // micro-tile id: 4h x 4n
        int hg = mt >> 4;              // 0..127
        int sg = mt & 15;              // 0..15
        int h0 = hg * 4, nn_ = sg * 4;
        float rr[4][4];
        #pragma unroll
        for (int j = 0; j < 4; j++) {
            float4 f = *(const float4*)(refb + (size_t)(h0 + j) * NNODE + nn_);
            rr[j][0] = f.x; rr[j][1] = f.y; rr[j][2] = f.z; rr[j][3] = f.w;
        }
        #pragma unroll
        for (int c = 0; c < 4; c++) {
            int n = nn_ + c;
            ushort4 p;
            p.x = f2bf(rr[0][c]); p.y = f2bf(rr[1][c]);
            p.z = f2bf(rr[2][c]); p.w = f2bf(rr[3][c]);
            int idx = n * 512 + ((((h0 >> 3) ^ (n & 7)) << 3) + (h0 & 7));
            *(ushort4*)&Bs[idx] = p;
        }
    }
    __syncthreads();

    // ---- GEMM: acc[m][nf] = sum_k W[row][k] * ref[k][n] ----
    const int wo = wave * 64;
    f32x4 acc[4][4];
    #pragma unroll
    for (int m = 0; m < 4; m++)
        #pragma unroll
        for (int nf = 0; nf < 4; nf++)
            acc[m][nf] = (f32x4){0.f, 0.f, 0.f, 0.f};

    for (int kk = 0; kk < 512; kk += 32) {
        bf16x8 A[4], B[4];
        #pragma unroll
        for (int m = 0; m < 4; m++) {
            int row = wo + m * 16 + cl;
            A[m] = *(const bf16x8*)(Wb + (size_t)row * 512 + kk + gr * 8);
        }
        #pragma unroll
        for (int nf = 0; nf < 4; nf++) {
            int n = nf * 16 + cl;
            int k = kk + gr * 8;
            int idx = n * 512 + (((k >> 3) ^ (n & 7)) << 3);
            B[nf] = *(const bf16x8*)&Bs[idx];
        }
        #pragma unroll
        for (int m = 0; m < 4; m++)
            #pragma unroll
            for (int nf = 0; nf < 4; nf++)
                acc[m][nf] = __builtin_amdgcn_mfma_f32_16x16x32_bf16(A[m], B[nf], acc[m][nf], 0, 0, 0);
    }

    // ---- scores: sp[nf] = sum over this wave's rows of v[o]*tanh(u1[o]+u2[o][n]) ----
    float sp[4] = {0.f, 0.f, 0.f, 0.f};
    #pragma unroll
    for (int m = 0; m < 4; m++) {
        #pragma unroll
        for (int r = 0; r < 4; r++) {
            int o = wo + m * 16 + gr * 4 + r;
            float uo = u1l[o];
            float vo = vl[o];
            #pragma unroll
            for (int nf = 0; nf < 4; nf++)
                sp[nf] += vo * tanh_fast(uo + acc[m][nf][r]);
        }
    }
    #pragma unroll
    for (int nf = 0; nf < 4; nf++) {
        sp[nf] += __shfl_xor(sp[nf], 16);
        sp[nf] += __shfl_xor(sp[nf], 32);
    }
    if (lane < 16) {
        #pragma unroll
        for (int nf = 0; nf < 4; nf++)
            sred[wave][nf * 16 + lane] = sp[nf];
    }
    __syncthreads();

    // ---- local masked softmax over the 64 nodes (wave 0) ----
    if (tid < 64) {
        float u = 0.f;
        #pragma unroll
        for (int w = 0; w < 8; w++) u += sred[w][tid];
        u -= 1e8f * (float)mask[b * NNODE + n0 + tid];
        float mx = u;
        #pragma unroll
        for (int off = 1; off < 64; off <<= 1) mx = fmaxf(mx, __shfl_xor(mx, off));
        float wv = __expf(u - mx);
        float s = wv;
        #pragma unroll
        for (int off = 1; off < 64; off <<= 1) s += __shfl_xor(s, off);
        wts[tid] = wv;
        if (tid == 0) { stats[bid * 2] = mx; stats[bid * 2 + 1] = s; }
    }
    __syncthreads();

    // ---- d_t[o] = sum_n acc[o][n] * w_n  (from registers) ----
    float wc[4];
    #pragma unroll
    for (int nf = 0; nf < 4; nf++) wc[nf] = wts[nf * 16 + cl];
    float* dout = dts + (size_t)bid * HDIM;
    #pragma unroll
    for (int m = 0; m < 4; m++) {
        #pragma unroll
        for (int r = 0; r < 4; r++) {
            float d = acc[m][0][r] * wc[0] + acc[m][1][r] * wc[1]
                    + acc[m][2][r] * wc[2] + acc[m][3][r] * wc[3];
            d += __shfl_xor(d, 1);
            d += __shfl_xor(d, 2);
            d += __shfl_xor(d, 4);
            d += __shfl_xor(d, 8);
            if (cl == 0) dout[wo + m * 16 + gr * 4 + r] = d;
        }
    }
}

// ---- kernel 4: combine 16 tiles per batch ----
__global__ void k_comb(const float* __restrict__ stats, const float* __restrict__ dts,
                       const float* __restrict__ bref, float* __restrict__ out) {
    __shared__ float sm[NT], sl[NT];
    int b = blockIdx.x, tid = threadIdx.x;
    if (tid < NT) {
        sm[tid] = stats[(b * NT + tid) * 2];
        sl[tid] = stats[(b * NT + tid) * 2 + 1];
    }
    __syncthreads();
    float m = -3.4e38f;
    #pragma unroll
    for (int t = 0; t < NT; t++) m = fmaxf(m, sm[t]);
    float sc[NT];
    float L = 0.f;
    #pragma unroll
    for (int t = 0; t < NT; t++) { sc[t] = __expf(sm[t] - m); L += sc[t] * sl[t]; }
    float inv = 1.0f / L;
    float acc = 0.f;
    #pragma unroll
    for (int t = 0; t < NT; t++)
        acc += sc[t] * dts[((size_t)b * NT + t) * HDIM + tid];
    out[b * HDIM + tid] = acc * inv + bref[tid];
}

extern "C" void kernel_launch(void* const* d_in, const int* in_sizes, int n_in,
                              void* d_out, int out_size, void* d_ws, size_t ws_size,
                              hipStream_t stream) {
    const float* q    = (const float*)d_in[0];
    const float* ref  = (const float*)d_in[1];
    const int*   mask = (const int*)d_in[2];
    const float* v    = (const float*)d_in[3];
    const float* Wq   = (const float*)d_in[4];
    const float* bq   = (const float*)d_in[5];
    const float* Wref = (const float*)d_in[6];
    const float* bref = (const float*)d_in[7];
    float* out = (float*)d_out;

    char* ws = (char*)d_ws;
    unsigned short* wbf  = (unsigned short*)ws;                       // 512*512*2 = 524288 B
    float* u1b   = (float*)(ws + 524288);                             // 128*512*4 = 262144 B
    float* stats = (float*)(ws + 524288 + 262144);                    // 2048*2*4  = 16384 B
    float* dts   = (float*)(ws + 524288 + 262144 + 16384);            // 2048*512*4 = 4 MB

    k_cast_w<<<256, 256, 0, stream>>>(Wref, wbf);
    k_u1<<<BS, HDIM, 0, stream>>>(q, Wq, bq, bref, u1b);
    k_main<<<NBLK, 512, 0, stream>>>(ref, mask, v, wbf, u1b, stats, dts);
    k_comb<<<BS, HDIM, 0, stream>>>(stats, dts, bref, out);
}